// Round 1
// baseline (163.375 us; speedup 1.0000x reference)
//
#include <hip/hip_runtime.h>
#include <stdint.h>

// DTM layer: B=4, C=3, H=W=64. Grid is a unit-spaced integer lattice, so
// pairwise dist^2 = (di)^2 + (dj)^2 (integer, <= 7938). We counting-sort all
// 127x127 relative offsets by d^2 once per launch (device-side, no static
// state), then each pixel walks that list accumulating weights until the
// running sum crosses bound = 0.05 * sum(w); interpolate within the crossing
// element exactly as the reference does. max_k clip provably never binds
// (sorted-ascending prefix sums are pointwise minimal), so it's skipped.

#define HW   4096
#define NOFF 16129   // 127*127 relative offsets
#define NBIN 8192    // d2 max = 63^2+63^2 = 7938 < 8192

__global__ void count_kernel(int* __restrict__ cnt) {
    int idx = blockIdx.x * blockDim.x + threadIdx.x;
    if (idx >= NOFF) return;
    int di = idx / 127 - 63;
    int dj = idx % 127 - 63;
    int d2 = di * di + dj * dj;
    atomicAdd(&cnt[d2], 1);
}

// single-block exclusive prefix sum over NBIN bins (1024 thr x 8 bins each)
__global__ __launch_bounds__(1024) void scan_kernel(int* __restrict__ cnt) {
    __shared__ int part[1024];
    int tid = threadIdx.x;
    int local[8];
    int s = 0;
    int base = tid * 8;
    #pragma unroll
    for (int k = 0; k < 8; ++k) { local[k] = cnt[base + k]; s += local[k]; }
    part[tid] = s;
    __syncthreads();
    for (int off = 1; off < 1024; off <<= 1) {
        int v = part[tid];
        int u = (tid >= off) ? part[tid - off] : 0;
        __syncthreads();
        part[tid] = v + u;
        __syncthreads();
    }
    int run = (tid == 0) ? 0 : part[tid - 1];
    #pragma unroll
    for (int k = 0; k < 8; ++k) { int c = local[k]; cnt[base + k] = run; run += c; }
}

__global__ void scatter_kernel(int* __restrict__ cnt, uint32_t* __restrict__ list) {
    int idx = blockIdx.x * blockDim.x + threadIdx.x;
    if (idx >= NOFF) return;
    int di = idx / 127 - 63;
    int dj = idx % 127 - 63;
    int d2 = di * di + dj * dj;
    int pos = atomicAdd(&cnt[d2], 1);
    // pack: d2 in bits [14..26], (di+63) in [7..13], (dj+63) in [0..6]
    list[pos] = ((uint32_t)d2 << 14) | ((uint32_t)(di + 63) << 7) | (uint32_t)(dj + 63);
}

// one 64-thread block per (b,c,row); lane = column. Weights for the (b,c)
// slice staged in LDS; bound computed by wave reduction.
__global__ __launch_bounds__(64) void dtm_kernel(const float* __restrict__ x,
                                                 const uint32_t* __restrict__ list,
                                                 float* __restrict__ out) {
    __shared__ float w[HW];
    int bc  = blockIdx.x >> 6;   // (b,c) slice, 0..BC-1
    int pi  = blockIdx.x & 63;   // row
    int tid = threadIdx.x;       // column

    const float4* xb = (const float4*)(x + (size_t)bc * HW);
    float4* wv = (float4*)w;
    float s = 0.f;
    #pragma unroll
    for (int k = 0; k < 16; ++k) {
        int m = k * 64 + tid;
        float4 v = xb[m];
        wv[m] = v;
        s += (v.x + v.y) + (v.z + v.w);
    }
    #pragma unroll
    for (int off = 32; off >= 1; off >>= 1) s += __shfl_down(s, off, 64);
    float bound = 0.05f * __shfl(s, 0, 64);
    __syncthreads();

    int pj = tid;
    float cum = 0.f, cumd = 0.f, val = 0.f;
    bool done = false;
    for (int i = 0; i < NOFF && !done; ++i) {
        uint32_t e = list[i];
        int d2 = (int)(e >> 14);
        int qi = pi + (int)((e >> 7) & 127u) - 63;
        int qj = pj + (int)(e & 127u) - 63;
        if ((unsigned)qi < 64u && (unsigned)qj < 64u) {
            float wq = w[(qi << 6) | qj];
            float nc = cum + wq;
            if (nc >= bound) {
                val = cumd + (float)d2 * (bound - cum);
                done = true;
            } else {
                cum  = nc;
                cumd = fmaf((float)d2, wq, cumd);
            }
        }
    }
    out[(size_t)bc * HW + (pi << 6) + pj] = sqrtf(val / bound);
}

extern "C" void kernel_launch(void* const* d_in, const int* in_sizes, int n_in,
                              void* d_out, int out_size, void* d_ws, size_t ws_size,
                              hipStream_t stream) {
    const float* x = (const float*)d_in[0];
    float* out = (float*)d_out;

    int* cnt = (int*)d_ws;
    uint32_t* list = (uint32_t*)((char*)d_ws + NBIN * sizeof(int));

    int BC = in_sizes[0] / HW;   // 12 for (4,3,64,64)

    hipMemsetAsync(cnt, 0, NBIN * sizeof(int), stream);
    count_kernel<<<(NOFF + 255) / 256, 256, 0, stream>>>(cnt);
    scan_kernel<<<1, 1024, 0, stream>>>(cnt);
    scatter_kernel<<<(NOFF + 255) / 256, 256, 0, stream>>>(cnt, list);
    dtm_kernel<<<BC * 64, 64, 0, stream>>>(x, list, out);
}

// Round 2
// 159.419 us; speedup vs baseline: 1.0248x; 1.0248x over previous
//
#include <hip/hip_runtime.h>
#include <stdint.h>

// DTM layer: B=4, C=3, H=W=64. Grid is a unit-spaced integer lattice, so
// pairwise dist^2 = (di)^2 + (dj)^2 (integer, <= 7938). One single-block
// kernel counting-sorts all 127x127 relative offsets by d^2 (LDS histogram +
// block scan + scatter). The dtm kernel walks the sorted list per pixel,
// accumulating weights until the running sum crosses bound = 0.05*sum(w),
// interpolating within the crossing element exactly as the reference does.
// Within an equal-d2 shell the result is order-invariant, so counting-sort
// order is exact. max_k clip provably never binds (ascending-sorted prefix
// sums are pointwise minimal) and is skipped.

#define HW    4096
#define NOFF  16129   // 127*127
#define NPAD  16384   // list padded to full 1024-entry chunks (tail zeroed)
#define NBIN  8192    // max d2 = 63^2+63^2 = 7938

// ---- build: counting sort of offsets by d2, one block of 1024 threads ----
__global__ __launch_bounds__(1024) void build_kernel(uint32_t* __restrict__ list) {
    __shared__ int hist[NBIN];   // 32 KB
    __shared__ int part[1024];
    int tid = threadIdx.x;

    for (int k = tid; k < NBIN; k += 1024) hist[k] = 0;
    __syncthreads();

    for (int idx = tid; idx < NOFF; idx += 1024) {
        int di = idx / 127 - 63;
        int dj = idx % 127 - 63;
        atomicAdd(&hist[di * di + dj * dj], 1);
    }
    __syncthreads();

    // exclusive scan over 8192 bins: 8 bins/thread + Hillis-Steele block scan
    int local[8];
    int s = 0;
    int base = tid * 8;
    #pragma unroll
    for (int k = 0; k < 8; ++k) { local[k] = hist[base + k]; s += local[k]; }
    part[tid] = s;
    __syncthreads();
    for (int off = 1; off < 1024; off <<= 1) {
        int v = part[tid];
        int u = (tid >= off) ? part[tid - off] : 0;
        __syncthreads();
        part[tid] = v + u;
        __syncthreads();
    }
    int run = (tid == 0) ? 0 : part[tid - 1];
    #pragma unroll
    for (int k = 0; k < 8; ++k) { int c = local[k]; hist[base + k] = run; run += c; }
    __syncthreads();

    for (int idx = tid; idx < NOFF; idx += 1024) {
        int di = idx / 127 - 63;
        int dj = idx % 127 - 63;
        int d2 = di * di + dj * dj;
        int pos = atomicAdd(&hist[d2], 1);
        // pack: d2 in [14..26], (di+63) in [7..13], (dj+63) in [0..6]
        list[pos] = ((uint32_t)d2 << 14) | ((uint32_t)(di + 63) << 7) | (uint32_t)(dj + 63);
    }
    // zero tail: decodes to di=dj=-63 -> always out of range -> wq = 0
    for (int idx = NOFF + tid; idx < NPAD; idx += 1024) list[idx] = 0;
}

// ---- dtm: one 64-thread block per (b,c,row); lane = column ----
__global__ __launch_bounds__(64) void dtm_kernel(const float* __restrict__ x,
                                                 const uint32_t* __restrict__ list,
                                                 float* __restrict__ out) {
    __shared__ float w[HW];          // 16 KB
    __shared__ uint32_t buf[1024];   // 4 KB list chunk
    int bc  = blockIdx.x >> 6;
    int pi  = blockIdx.x & 63;   // row
    int tid = threadIdx.x;       // column

    // stage weights + reduce for bound
    const float4* xb = (const float4*)(x + (size_t)bc * HW);
    float4* wv = (float4*)w;
    float s = 0.f;
    #pragma unroll
    for (int k = 0; k < 16; ++k) {
        int m = k * 64 + tid;
        float4 v = xb[m];
        wv[m] = v;
        s += (v.x + v.y) + (v.z + v.w);
    }
    #pragma unroll
    for (int off = 32; off >= 1; off >>= 1) s += __shfl_down(s, off, 64);
    float bound = 0.05f * __shfl(s, 0, 64);
    __syncthreads();

    float cum = 0.f, cumd = 0.f, val = 0.f;
    bool done = false;

    for (int base = 0; base < NPAD; base += 1024) {
        // stage 1024-entry chunk: 4 x uint4 per lane, coalesced
        const uint4* lp = (const uint4*)(list + base);
        uint4* bp = (uint4*)buf;
        #pragma unroll
        for (int k = 0; k < 4; ++k) bp[k * 64 + tid] = lp[k * 64 + tid];
        __syncthreads();

        for (int i = 0; i < 1024; i += 8) {
            #pragma unroll
            for (int k = 0; k < 8; ++k) {
                // entry is wave-uniform: scalarize decode (SALU is free)
                uint32_t e = __builtin_amdgcn_readfirstlane(buf[i + k]);
                int d2f = (int)(e >> 14);
                int qi  = pi + (int)((e >> 7) & 127u) - 63;
                int qj  = tid + (int)(e & 127u) - 63;
                bool valid = ((unsigned)qi < 64u) & ((unsigned)qj < 64u);
                float wq = w[((qi & 63) << 6) | (qj & 63)];
                wq = (valid && !done) ? wq : 0.f;
                float nc = cum + wq;
                if (!done && nc >= bound) {
                    val = fmaf((float)d2f, bound - cum, cumd);
                    done = true;
                }
                cumd = fmaf((float)d2f, wq, cumd);
                cum = nc;
            }
            if (__all(done)) goto finish;
        }
        __syncthreads();
    }
finish:
    out[(size_t)bc * HW + (pi << 6) + tid] = sqrtf(val / bound);
}

extern "C" void kernel_launch(void* const* d_in, const int* in_sizes, int n_in,
                              void* d_out, int out_size, void* d_ws, size_t ws_size,
                              hipStream_t stream) {
    const float* x = (const float*)d_in[0];
    float* out = (float*)d_out;
    uint32_t* list = (uint32_t*)d_ws;   // NPAD entries = 64 KB

    int BC = in_sizes[0] / HW;   // 12 for (4,3,64,64)

    build_kernel<<<1, 1024, 0, stream>>>(list);
    dtm_kernel<<<BC * 64, 64, 0, stream>>>(x, list, out);
}

// Round 3
// 104.978 us; speedup vs baseline: 1.5563x; 1.5186x over previous
//
#include <hip/hip_runtime.h>
#include <stdint.h>

// DTM layer: B=4, C=3, H=W=64. Grid is a unit-spaced integer lattice, so
// pairwise dist^2 = (di)^2 + (dj)^2 (integer, <= 7938). The distance-sorted
// offset list is a COMPILE-TIME constant (constexpr counting sort -> device
// rodata): per pixel, walk offsets in increasing d2, accumulating weights
// until the running sum crosses bound = 0.05*sum(w), interpolating within the
// crossing element exactly as the reference. Within an equal-d2 shell the
// result is order-invariant, so counting-sort order is exact. The max_k clip
// provably never binds (ascending-sorted prefix sums are pointwise minimal).
//
// Perf structure (round-3): entries are held in registers (one per lane,
// coalesced load, prefetched a group ahead) and broadcast via v_readlane
// (no LDS pipe, scalar decode on SALU). The per-entry weight gathers are
// issued as 16 independent ds_read_b32 into a register array (phase 1),
// then a branchless cndmask accumulate chain runs (phase 2). This removes
// the round-2 two-level dependent-LDS chain that serialized ~500 cyc/entry.

#define HW    4096
#define NOFF  16129   // 127*127
#define NPAD  16384   // padded to 64-entry groups; pad decodes to invalid col
#define NBIN  8192    // max d2 = 63^2+63^2 = 7938

struct Tables {
    uint32_t off[NPAD];  // (di+63)<<7 | (dj+63)
    float    d2f[NPAD];  // (float)d2, pre-converted
};

constexpr Tables make_tables() {
    Tables t{};
    int cnt[NBIN] = {};
    for (int idx = 0; idx < NOFF; ++idx) {
        int di = idx / 127 - 63, dj = idx % 127 - 63;
        cnt[di * di + dj * dj]++;
    }
    int run = 0;
    for (int b = 0; b < NBIN; ++b) { int c = cnt[b]; cnt[b] = run; run += c; }
    for (int idx = 0; idx < NOFF; ++idx) {
        int di = idx / 127 - 63, dj = idx % 127 - 63;
        int d2 = di * di + dj * dj;
        int pos = cnt[d2]++;
        t.off[pos] = (uint32_t)((di + 63) << 7) | (uint32_t)(dj + 63);
        t.d2f[pos] = (float)d2;
    }
    for (int p = NOFF; p < NPAD; ++p) {
        t.off[p] = 127u;      // dj field = 127 -> qj = tid+64 >= 64: always invalid
        t.d2f[p] = 0.0f;
    }
    return t;
}

__device__ const Tables g_tables = make_tables();

// one 64-thread block per (b,c,row); lane = column
__global__ __launch_bounds__(64) void dtm_kernel(const float* __restrict__ x,
                                                 float* __restrict__ out) {
    __shared__ float w[HW];   // 16 KB
    int bc  = blockIdx.x >> 6;
    int pi  = blockIdx.x & 63;   // row (wave-uniform)
    int tid = threadIdx.x;       // column

    // stage weights + wave-reduce for bound
    const float4* xb = (const float4*)(x + (size_t)bc * HW);
    float4* wv4 = (float4*)w;
    float s = 0.f;
    #pragma unroll
    for (int k = 0; k < 16; ++k) {
        int m = k * 64 + tid;
        float4 v = xb[m];
        wv4[m] = v;
        s += (v.x + v.y) + (v.z + v.w);
    }
    #pragma unroll
    for (int off = 32; off >= 1; off >>= 1) s += __shfl_down(s, off, 64);
    float bound = 0.05f * __shfl(s, 0, 64);
    __syncthreads();

    const uint32_t* __restrict__ offp = g_tables.off;
    const float*    __restrict__ d2p  = g_tables.d2f;

    float rem = bound;        // bound - cum
    float cumd = 0.f, val = 0.f;
    bool done = false;

    // preload first group into registers (one entry per lane)
    uint32_t ew = offp[tid];
    float    dw = d2p[tid];

    for (int base = 0; base < NPAD; base += 64) {
        uint32_t ew_cur = ew;
        float    dw_cur = dw;
        int nb = base + 64;
        if (nb < NPAD) {          // prefetch next group
            ew = offp[nb + tid];
            dw = d2p[nb + tid];
        }
        #pragma unroll
        for (int g = 0; g < 4; ++g) {
            // phase 1: 16 independent LDS gathers (addresses from readlane,
            // no LDS->LDS dependence; compiler can batch the ds_reads)
            float wqs[16];
            #pragma unroll
            for (int k = 0; k < 16; ++k) {
                uint32_t e = (uint32_t)__builtin_amdgcn_readlane((int)ew_cur, g * 16 + k);
                int qi = pi + (int)((e >> 7) & 127u) - 63;   // wave-uniform (SALU)
                int qj = tid + (int)(e & 127u) - 63;
                float wq = w[(((unsigned)qi & 63u) << 6) | ((unsigned)qj & 63u)];
                bool ok = ((unsigned)qi < 64u) & ((unsigned)qj < 64u);
                wqs[k] = ok ? wq : 0.f;
            }
            // phase 2: branchless accumulate chain
            #pragma unroll
            for (int k = 0; k < 16; ++k) {
                float d2f = __uint_as_float(
                    (uint32_t)__builtin_amdgcn_readlane(__float_as_int(dw_cur), g * 16 + k));
                float wq = done ? 0.f : wqs[k];
                bool cross = (!done) & (wq >= rem);
                float cv = fmaf(d2f, rem, cumd);   // cumd_before + d2*(bound-cum_before)
                val  = cross ? cv : val;
                done = done | cross;
                cumd = fmaf(d2f, wq, cumd);
                rem  = rem - wq;
            }
            if (__all(done)) goto finish;
        }
    }
finish:
    out[(size_t)bc * HW + (pi << 6) + tid] = sqrtf(val / bound);
}

extern "C" void kernel_launch(void* const* d_in, const int* in_sizes, int n_in,
                              void* d_out, int out_size, void* d_ws, size_t ws_size,
                              hipStream_t stream) {
    const float* x = (const float*)d_in[0];
    float* out = (float*)d_out;
    int BC = in_sizes[0] / HW;   // 12 for (4,3,64,64)
    dtm_kernel<<<BC * 64, 64, 0, stream>>>(x, out);
}

// Round 4
// 71.045 us; speedup vs baseline: 2.2996x; 1.4776x over previous
//
#include <hip/hip_runtime.h>
#include <stdint.h>

// DTM layer: B=4, C=3, H=W=64. Unit-spaced lattice => dist^2 = di^2 + dj^2.
// The distance-sorted offset list is a compile-time constant (constexpr
// counting sort -> rodata). Per pixel: walk offsets in increasing d2,
// accumulate weight until crossing bound = 0.05*sum(w), interpolate within
// the crossing element (algebraically identical to the reference's inclusive
// formulation). Equal-d2 shells are order-invariant; max_k clip never binds.
//
// Round-4 structure (fixes 4.4% occupancy): one 1024-thread block (16 waves)
// per (b,c,row). Phase A: wave v computes 64-entry chunk-v partial sums
// (mass, d2*mass) for all 64 pixels of the row -> 16x wave parallelism over
// the formerly-serial walk. Phase B: wave 0 scans the 16 chunk summaries per
// pixel, then walks only the 64 entries of the per-lane crossing chunk.
// A __any-guarded fallback loop preserves exactness for ulp-boundary or
// beyond-1024-entry crossings (mathematically ~never taken: 1024 entries
// cover the worst corner-pixel crossing with ~5 sigma margin).

#define HW     4096
#define NOFF   16129   // 127*127
#define NPAD   16384
#define NBIN   8192    // max d2 = 63^2+63^2 = 7938
#define NCHUNK 16      // speculative chunks of 64 entries = 1024 entries

struct Ent { uint32_t off; float d2; };   // off = (di+63)<<7 | (dj+63)
struct Tables { Ent e[NPAD]; };

constexpr Tables make_tables() {
    Tables t{};
    int cnt[NBIN] = {};
    for (int idx = 0; idx < NOFF; ++idx) {
        int di = idx / 127 - 63, dj = idx % 127 - 63;
        cnt[di * di + dj * dj]++;
    }
    int run = 0;
    for (int b = 0; b < NBIN; ++b) { int c = cnt[b]; cnt[b] = run; run += c; }
    for (int idx = 0; idx < NOFF; ++idx) {
        int di = idx / 127 - 63, dj = idx % 127 - 63;
        int d2 = di * di + dj * dj;
        int pos = cnt[d2]++;
        t.e[pos].off = (uint32_t)((di + 63) << 7) | (uint32_t)(dj + 63);
        t.e[pos].d2  = (float)d2;
    }
    for (int p = NOFF; p < NPAD; ++p) {
        t.e[p].off = 127u;   // dj field = 127 -> qj = lane+64 >= 64: invalid
        t.e[p].d2  = 0.0f;
    }
    return t;
}

__device__ const Tables g_t = make_tables();

__global__ __launch_bounds__(1024) void dtm_kernel(const float* __restrict__ x,
                                                   float* __restrict__ out) {
    __shared__ float  w[HW];                 // 16 KB
    __shared__ float2 summ[NCHUNK][64];      // 8 KB chunk partials
    __shared__ float  red[16];

    int bc   = blockIdx.x >> 6;
    int pi   = blockIdx.x & 63;   // row (uniform)
    int tid  = threadIdx.x;
    int lane = tid & 63;          // pixel column (phase A: also column)
    int wv   = tid >> 6;          // wave id 0..15

    // ---- stage weights (1024 threads x float4) + block-reduce for bound ----
    const float4* xb = (const float4*)(x + (size_t)bc * HW);
    float4 v = xb[tid];
    ((float4*)w)[tid] = v;
    float s = (v.x + v.y) + (v.z + v.w);
    #pragma unroll
    for (int off = 32; off >= 1; off >>= 1) s += __shfl_down(s, off, 64);
    if (lane == 0) red[wv] = s;
    __syncthreads();

    // ---- phase A: wave wv -> chunk-wv partial (mass, d2mass) per pixel ----
    {
        int base = __builtin_amdgcn_readfirstlane(wv) << 6;  // uniform
        float mass = 0.f, d2m = 0.f;
        #pragma unroll 8
        for (int k = 0; k < 64; ++k) {
            Ent e = g_t.e[base + k];        // uniform index -> scalar load
            int qi = pi + (int)((e.off >> 7) & 127u) - 63;   // uniform (SALU)
            int qj = lane + (int)(e.off & 127u) - 63;
            bool ok = ((unsigned)qi < 64u) & ((unsigned)qj < 64u);
            float wq = w[(((unsigned)qi & 63u) << 6) | ((unsigned)qj & 63u)];
            wq = ok ? wq : 0.f;
            mass += wq;
            d2m = fmaf(e.d2, wq, d2m);
        }
        summ[wv][lane] = make_float2(mass, d2m);
    }
    __syncthreads();
    if (wv != 0) return;

    // ---- phase B (wave 0 only): per-lane pixel = column `lane` of row pi ----
    float bound = 0.f;
    #pragma unroll
    for (int i = 0; i < 16; ++i) bound += red[i];
    bound *= 0.05f;

    // scan chunk summaries: find crossing chunk, rem/cumd before it
    float rem = bound, cumd = 0.f;
    int cstar = NCHUNK;
    bool found = false;
    #pragma unroll
    for (int c = 0; c < NCHUNK; ++c) {
        float2 p = summ[c][lane];
        bool cross = (!found) & (p.x >= rem);
        bool adv   = (!found) & (!cross);
        cstar = cross ? c : cstar;
        found = found | cross;
        rem   = adv ? rem - p.x : rem;
        cumd  = adv ? cumd + p.y : cumd;
    }

    // walk the 64 entries of the crossing chunk (per-lane divergent data,
    // uniform trip count). cstar==NCHUNK lanes (never in practice) continue
    // seamlessly at entry 1024.
    float val = 0.f;
    bool done = false;
    int pos = cstar << 6;
    #pragma unroll 8
    for (int k = 0; k < 64; ++k) {
        Ent e = g_t.e[pos + k];
        int qi = pi + (int)((e.off >> 7) & 127u) - 63;
        int qj = lane + (int)(e.off & 127u) - 63;
        bool ok = ((unsigned)qi < 64u) & ((unsigned)qj < 64u) & (!done);
        float wq = w[(((unsigned)qi & 63u) << 6) | ((unsigned)qj & 63u)];
        wq = ok ? wq : 0.f;
        bool cross = (!done) & (wq >= rem);
        float cv = fmaf(e.d2, rem, cumd);
        val  = cross ? cv : val;
        done = done | cross;
        cumd = fmaf(e.d2, wq, cumd);
        rem  = rem - wq;
    }
    pos += 64;

    // exact-correctness fallback (ulp-boundary chunk detection, or crossing
    // beyond the speculative window). Practically never taken.
    while (__any(!done)) {
        int idx = pos < NPAD ? pos : NPAD - 1;
        Ent e = g_t.e[idx];
        int qi = pi + (int)((e.off >> 7) & 127u) - 63;
        int qj = lane + (int)(e.off & 127u) - 63;
        bool ok = ((unsigned)qi < 64u) & ((unsigned)qj < 64u) & (!done);
        float wq = w[(((unsigned)qi & 63u) << 6) | ((unsigned)qj & 63u)];
        wq = ok ? wq : 0.f;
        bool cross = (!done) & ((wq >= rem) | (pos >= NPAD));
        float cv = fmaf(e.d2, rem, cumd);
        val  = cross ? cv : val;
        done = done | cross;
        cumd = fmaf(e.d2, wq, cumd);
        rem  = rem - wq;
        pos++;
    }

    out[(size_t)bc * HW + (pi << 6) + lane] = sqrtf(val / bound);
}

extern "C" void kernel_launch(void* const* d_in, const int* in_sizes, int n_in,
                              void* d_out, int out_size, void* d_ws, size_t ws_size,
                              hipStream_t stream) {
    const float* x = (const float*)d_in[0];
    float* out = (float*)d_out;
    int BC = in_sizes[0] / HW;   // 12 for (4,3,64,64)
    dtm_kernel<<<BC * 64, 1024, 0, stream>>>(x, out);
}